// Round 6
// baseline (222.211 us; speedup 1.0000x reference)
//
#include <hip/hip_runtime.h>
#include <hip/hip_bf16.h>
#include <stdint.h>

#define N_ROWS 4096
#define DIM    2048
#define BK     64
#define EPSF   1e-12f

typedef __bf16 bf16x8 __attribute__((ext_vector_type(8)));
typedef float  f32x4  __attribute__((ext_vector_type(4)));

typedef __attribute__((address_space(1))) void gv_t;
typedef __attribute__((address_space(3))) void lv_t;

__device__ __forceinline__ void gload_lds16(const void* g, void* l) {
    // async global->LDS, 16B per lane; LDS dest = wave-uniform base + lane*16
    __builtin_amdgcn_global_load_lds((gv_t*)g, (lv_t*)l, 16, 0, 0);
}

// round-to-nearest-even f32 -> bf16 bits
__device__ __forceinline__ unsigned short f2bf(float f) {
    unsigned u = __float_as_uint(f);
    return (unsigned short)((u + 0x7FFFu + ((u >> 16) & 1u)) >> 16);
}

// ---------------------------------------------------------------------------
// Kernel 1: f32 -> bf16 convert, row sum-of-squares, init per-row atoms.
// One block per row; blocks [0,4096) = modal1, [4096,8192) = modal2.
// Fully-coalesced: lane i loads float4 at [i] and [i+256] (16 B/lane each).
// ---------------------------------------------------------------------------
__global__ __launch_bounds__(256) void prep_kernel(
    const float* __restrict__ m1, const float* __restrict__ m2,
    unsigned short* __restrict__ abf, unsigned short* __restrict__ bbf,
    float* __restrict__ sq1, float* __restrict__ sq2,
    unsigned* __restrict__ ap_bits, unsigned* __restrict__ an_bits) {
    const int blk = blockIdx.x;
    const bool isB = blk >= N_ROWS;
    const int r = isB ? blk - N_ROWS : blk;
    const float* src = (isB ? m2 : m1) + (size_t)r * DIM;
    unsigned short* dst = (isB ? bbf : abf) + (size_t)r * DIM;
    const int tid = threadIdx.x;

    const float4* s4 = (const float4*)src;        // 2048 f32 = 512 float4
    float4 v0 = s4[tid];
    float4 v1 = s4[tid + 256];
    float acc = v0.x*v0.x + v0.y*v0.y + v0.z*v0.z + v0.w*v0.w
              + v1.x*v1.x + v1.y*v1.y + v1.z*v1.z + v1.w*v1.w;

    uint2 p0, p1;
    p0.x = (unsigned)f2bf(v0.x) | ((unsigned)f2bf(v0.y) << 16);
    p0.y = (unsigned)f2bf(v0.z) | ((unsigned)f2bf(v0.w) << 16);
    p1.x = (unsigned)f2bf(v1.x) | ((unsigned)f2bf(v1.y) << 16);
    p1.y = (unsigned)f2bf(v1.z) | ((unsigned)f2bf(v1.w) << 16);
    *(uint2*)(dst + tid * 4)         = p0;   // elems [4t,4t+4)
    *(uint2*)(dst + (tid + 256) * 4) = p1;   // elems [4(t+256),...)

    // wave64 reduce, then cross-wave via LDS
    for (int s = 32; s > 0; s >>= 1) acc += __shfl_down(acc, s);
    __shared__ float red[4];
    if ((tid & 63) == 0) red[tid >> 6] = acc;
    __syncthreads();
    if (tid == 0) {
        float* sq = isB ? sq2 : sq1;
        sq[r] = red[0] + red[1] + red[2] + red[3];
        if (!isB) {
            ap_bits[r] = 0u;           // max over positive floats: 0.0f = -inf stand-in
            an_bits[r] = 0x7f800000u;  // +inf
        }
    }
}

// ---------------------------------------------------------------------------
// Kernel 2: fused bf16 MFMA GEMM (A·B^T) + distance + masked max/min + atomics.
// m97-exact geometry: 128x128 tile, BK=64, 4 waves, acc[4][4], 32 KB LDS,
// 32 MFMA + 16 ds_read_b128 + 8 gload_lds per thread per K-tile, 2 barriers.
// ---------------------------------------------------------------------------
__global__ __launch_bounds__(256) void dist_gemm_kernel(
    const unsigned short* __restrict__ A, const unsigned short* __restrict__ B,
    const float* __restrict__ sq1, const float* __restrict__ sq2,
    const int* __restrict__ tgt,
    unsigned* __restrict__ ap_bits, unsigned* __restrict__ an_bits) {
    __shared__ unsigned short As[128 * BK];   // 16 KB
    __shared__ unsigned short Bs[128 * BK];   // 16 KB

    const int tid  = threadIdx.x;
    const int w    = tid >> 6;
    const int lane = tid & 63;
    const int wr   = w >> 1, wc = w & 1;      // wave quadrant (2x2 of 64x64)
    const int l15  = lane & 15, lhi = lane >> 4;
    const int brow = blockIdx.y * 128, bcol = blockIdx.x * 128;

    // staging: chunk = 1 KB = 8 rows x 64 bf16; lane l -> row l>>3, elem (l&7)*8
    const int srow  = lane >> 3;
    const int skoff = (lane & 7) * 8;

    f32x4 acc[4][4] = {};

    for (int kt = 0; kt < DIM; kt += BK) {
#pragma unroll
        for (int c = 0; c < 4; ++c) {
            const int chunk = w + c * 4;       // wave w stages chunks w, w+4, w+8, w+12
            const unsigned short* ga = A + (size_t)(brow + chunk * 8 + srow) * DIM + kt + skoff;
            gload_lds16(ga, &As[chunk * 512]);
            const unsigned short* gb = B + (size_t)(bcol + chunk * 8 + srow) * DIM + kt + skoff;
            gload_lds16(gb, &Bs[chunk * 512]);
        }

        __syncthreads();   // drains vmcnt (global_load_lds) + barrier

#pragma unroll
        for (int kk = 0; kk < 2; ++kk) {
            bf16x8 af[4], bfr[4];
#pragma unroll
            for (int m = 0; m < 4; ++m)
                af[m] = *(const bf16x8*)&As[(wr * 64 + m * 16 + l15) * BK + kk * 32 + lhi * 8];
#pragma unroll
            for (int n = 0; n < 4; ++n)
                bfr[n] = *(const bf16x8*)&Bs[(wc * 64 + n * 16 + l15) * BK + kk * 32 + lhi * 8];

#pragma unroll
            for (int m = 0; m < 4; ++m)
#pragma unroll
                for (int n = 0; n < 4; ++n)
                    acc[m][n] = __builtin_amdgcn_mfma_f32_16x16x32_bf16(af[m], bfr[n], acc[m][n], 0, 0, 0);
        }

        __syncthreads();   // all waves done reading before next-tile overwrite
    }

    // ---- fused epilogue: dist = sqrt(max(s1 + s2 - 2*dot, EPS)); masked max/min ----
    int   tcol[4];
    float s2c[4];
#pragma unroll
    for (int n = 0; n < 4; ++n) {
        int col = bcol + wc * 64 + n * 16 + l15;
        tcol[n] = tgt[col];
        s2c[n]  = sq2[col];
    }
    const float INF = __uint_as_float(0x7f800000u);
#pragma unroll
    for (int m = 0; m < 4; ++m) {
#pragma unroll
        for (int reg = 0; reg < 4; ++reg) {
            // C/D layout (m89-verified): col = lane&15, row = (lane>>4)*4 + reg
            int   row  = brow + wr * 64 + m * 16 + lhi * 4 + reg;
            int   trow = tgt[row];
            float s1   = sq1[row];
            float pmax = 0.0f;   // dist > 0 always, so 0 works as -inf
            float nmin = INF;
#pragma unroll
            for (int n = 0; n < 4; ++n) {
                float d2 = s1 + s2c[n] - 2.0f * acc[m][n][reg];
                float dd = sqrtf(fmaxf(d2, EPSF));
                if (trow == tcol[n]) pmax = fmaxf(pmax, dd);
                else                 nmin = fminf(nmin, dd);
            }
            // reduce across the 16 lanes sharing this row
#pragma unroll
            for (int s = 1; s < 16; s <<= 1) {
                pmax = fmaxf(pmax, __shfl_xor(pmax, s));
                nmin = fminf(nmin, __shfl_xor(nmin, s));
            }
            if (l15 == 0) {
                // positive-float bits are monotone under unsigned compare
                atomicMax(&ap_bits[row], __float_as_uint(pmax));
                atomicMin(&an_bits[row], __float_as_uint(nmin));
            }
        }
    }
}

// ---------------------------------------------------------------------------
// Kernel 3: loss = mean(relu(ap - an + margin)); prec = mean(an > ap)
// ---------------------------------------------------------------------------
__global__ __launch_bounds__(256) void finalize_kernel(
    const unsigned* __restrict__ ap_bits, const unsigned* __restrict__ an_bits,
    const float* __restrict__ marginp, float* __restrict__ out) {
    const int tid = threadIdx.x;
    const float margin = marginp[0];
    float ls = 0.f, ps = 0.f;
    for (int i = tid; i < N_ROWS; i += 256) {
        float a = __uint_as_float(ap_bits[i]);
        float b = __uint_as_float(an_bits[i]);
        ls += fmaxf(a - b + margin, 0.0f);
        ps += (b > a) ? 1.0f : 0.0f;
    }
    for (int s = 32; s > 0; s >>= 1) {
        ls += __shfl_down(ls, s);
        ps += __shfl_down(ps, s);
    }
    __shared__ float sl[4], sp[4];
    if ((tid & 63) == 0) { sl[tid >> 6] = ls; sp[tid >> 6] = ps; }
    __syncthreads();
    if (tid == 0) {
        ls = sl[0] + sl[1] + sl[2] + sl[3];
        ps = sp[0] + sp[1] + sp[2] + sp[3];
        out[0] = ls / (float)N_ROWS;
        out[1] = ps / (float)N_ROWS;
    }
}

// ---------------------------------------------------------------------------
extern "C" void kernel_launch(void* const* d_in, const int* in_sizes, int n_in,
                              void* d_out, int out_size, void* d_ws, size_t ws_size,
                              hipStream_t stream) {
    const float* m1  = (const float*)d_in[0];
    const float* m2  = (const float*)d_in[1];
    const int*   tgt = (const int*)d_in[2];
    const float* mrg = (const float*)d_in[3];

    char* ws = (char*)d_ws;
    unsigned short* abf = (unsigned short*)ws;                         // 16 MB bf16 modal1
    unsigned short* bbf = (unsigned short*)(ws + 16777216);            // 16 MB bf16 modal2
    float*    sq1 = (float*)(ws + 33554432);                           // 16 KB
    float*    sq2 = (float*)(ws + 33554432 + 16384);                   // 16 KB
    unsigned* ap  = (unsigned*)(ws + 33554432 + 32768);                // 16 KB
    unsigned* an  = (unsigned*)(ws + 33554432 + 49152);                // 16 KB

    float* outp = (float*)d_out;

    prep_kernel<<<2 * N_ROWS, 256, 0, stream>>>(m1, m2, abf, bbf, sq1, sq2, ap, an);
    dim3 grid(N_ROWS / 128, N_ROWS / 128);
    dist_gemm_kernel<<<grid, 256, 0, stream>>>(abf, bbf, sq1, sq2, tgt, ap, an);
    finalize_kernel<<<1, 256, 0, stream>>>(ap, an, mrg, outp);
}

// Round 13
// 183.605 us; speedup vs baseline: 1.2103x; 1.2103x over previous
//
#include <hip/hip_runtime.h>
#include <hip/hip_bf16.h>
#include <stdint.h>

#define N_ROWS 4096
#define DIM    2048
#define NT     (DIM / 64)   // 32 K-tiles of BK=64
#define EPSF   1e-12f

typedef __bf16 bf16x8 __attribute__((ext_vector_type(8)));
typedef float  f32x4  __attribute__((ext_vector_type(4)));

typedef __attribute__((address_space(1))) void gv_t;
typedef __attribute__((address_space(3))) void lv_t;

__device__ __forceinline__ void gload_lds16(const void* g, void* l) {
    // async global->LDS, 16B/lane; LDS dest = wave-uniform base + lane*16
    __builtin_amdgcn_global_load_lds((gv_t*)g, (lv_t*)l, 16, 0, 0);
}

// round-to-nearest-even f32 -> bf16 bits
__device__ __forceinline__ unsigned short f2bf(float f) {
    unsigned u = __float_as_uint(f);
    return (unsigned short)((u + 0x7FFFu + ((u >> 16) & 1u)) >> 16);
}

// ---------------------------------------------------------------------------
// Kernel 1: f32 -> bf16 convert, row sum-of-squares, init per-row atoms.
// ---------------------------------------------------------------------------
__global__ __launch_bounds__(256) void prep_kernel(
    const float* __restrict__ m1, const float* __restrict__ m2,
    unsigned short* __restrict__ abf, unsigned short* __restrict__ bbf,
    float* __restrict__ sq1, float* __restrict__ sq2,
    unsigned* __restrict__ ap_bits, unsigned* __restrict__ an_bits) {
    const int blk = blockIdx.x;
    const bool isB = blk >= N_ROWS;
    const int r = isB ? blk - N_ROWS : blk;
    const float* src = (isB ? m2 : m1) + (size_t)r * DIM;
    unsigned short* dst = (isB ? bbf : abf) + (size_t)r * DIM;
    const int tid = threadIdx.x;

    const float4* s4 = (const float4*)src;
    float4 v0 = s4[tid];
    float4 v1 = s4[tid + 256];
    float acc = v0.x*v0.x + v0.y*v0.y + v0.z*v0.z + v0.w*v0.w
              + v1.x*v1.x + v1.y*v1.y + v1.z*v1.z + v1.w*v1.w;

    uint2 p0, p1;
    p0.x = (unsigned)f2bf(v0.x) | ((unsigned)f2bf(v0.y) << 16);
    p0.y = (unsigned)f2bf(v0.z) | ((unsigned)f2bf(v0.w) << 16);
    p1.x = (unsigned)f2bf(v1.x) | ((unsigned)f2bf(v1.y) << 16);
    p1.y = (unsigned)f2bf(v1.z) | ((unsigned)f2bf(v1.w) << 16);
    *(uint2*)(dst + tid * 4)         = p0;
    *(uint2*)(dst + (tid + 256) * 4) = p1;

    for (int s = 32; s > 0; s >>= 1) acc += __shfl_down(acc, s);
    __shared__ float red[4];
    if ((tid & 63) == 0) red[tid >> 6] = acc;
    __syncthreads();
    if (tid == 0) {
        float* sq = isB ? sq2 : sq1;
        sq[r] = red[0] + red[1] + red[2] + red[3];
        if (!isB) {
            ap_bits[r] = 0u;           // dist > 0, so 0.0f works as -inf for max
            an_bits[r] = 0x7f800000u;  // +inf
        }
    }
}

// ---------------------------------------------------------------------------
// Kernel 2: fused bf16 MFMA GEMM (A·B^T) + distance + masked max/min + atomics.
// 8-phase counted-vmcnt structure (T3+T4+T5+T1) + T2 XOR-swizzle.
// 256x256 tile, BK=64, 8 waves (2Mx4N), 512 threads, LDS 128KB, grid 256=1/CU.
// T2 (rule #21, both-sides-or-neither): LDS dest stays LINEAR (gload_lds
// constraint); the global SOURCE granule is permuted ((l&7)^(l>>3)), and the
// ds_read applies the same XOR ((R&7)*16B). Breaks the 16-way bank conflict
// of the 128B-row-stride layout (round-6 evidence: 25M conflicts) to 2-way.
// vmcnt(4)@ph2, vmcnt(2)@ph4 - never drain to 0 in the main loop.
// ---------------------------------------------------------------------------
__global__ __launch_bounds__(512) void dist_gemm_kernel(
    const unsigned short* __restrict__ A, const unsigned short* __restrict__ B,
    const float* __restrict__ sq1, const float* __restrict__ sq2,
    const int* __restrict__ tgt,
    unsigned* __restrict__ ap_bits, unsigned* __restrict__ an_bits) {
    __shared__ unsigned short As[2][256 * 64];   // 64 KB
    __shared__ unsigned short Bs[2][256 * 64];   // 64 KB

    const int tid  = threadIdx.x;
    const int w    = tid >> 6;            // wave 0..7
    const int lane = tid & 63;
    const int wr   = w >> 2, wc = w & 3;  // wave grid 2x4; wave owns 128x64 of C
    const int l15  = lane & 15, lhi = lane >> 4;
    const int swz8 = (l15 & 7) * 8;       // read-side XOR key (elements)

    // bijective XCD swizzle over the 16x16 grid (256 blocks, 256 % 8 == 0)
    const int bid  = blockIdx.y * 16 + blockIdx.x;
    const int swz  = (bid & 7) * 32 + (bid >> 3);
    const int brow = (swz >> 4) * 256, bcol = (swz & 15) * 256;

    // staging: chunk = 64 rows x 64 cols (8 KB); wave w covers rows [8w,8w+8)
    // of the chunk; lane l -> row 8w+(l>>3). Source granule PERMUTED by the
    // T2 involution: col elems ((l&7)^(l>>3))*8, so the linear LDS write at
    // (l&7)*16B leaves LDS[R][cb] = global[cb ^ ((R&7)<<4)].
    const int srow = w * 8 + (lane >> 3);
    const int scol = ((lane & 7) ^ (lane >> 3)) * 8;

#define STAGE_A(buf, c, kt1) gload_lds16(                                        \
        A + (size_t)(brow + (c) * 64 + srow) * DIM + (kt1) + scol,               \
        &As[buf][((c) * 64 + w * 8) * 64])
#define STAGE_B(buf, c, kt1) gload_lds16(                                        \
        B + (size_t)(bcol + (c) * 64 + srow) * DIM + (kt1) + scol,               \
        &Bs[buf][((c) * 64 + w * 8) * 64])
// read with the same XOR: R&7 == l15&7 for both A (R=wr*128+m*16+l15) and B
#define LDA(m, kk) (*(const bf16x8*)&As[cur][(wr * 128 + (m) * 16 + l15) * 64 + (((kk) * 32 + lhi * 8) ^ swz8)])
#define LDB(n, kk) (*(const bf16x8*)&Bs[cur][(wc * 64 + (n) * 16 + l15) * 64 + (((kk) * 32 + lhi * 8) ^ swz8)])
#define BAR() asm volatile("s_barrier" ::: "memory")
#define MFMA(a, b, c) __builtin_amdgcn_mfma_f32_16x16x32_bf16((a), (b), (c), 0, 0, 0)

    f32x4 acc[8][4] = {};

    // prologue: stage tile 0 in deadline order; keep A1,A3 (ph3 data) in flight
    STAGE_B(0, 0, 0); STAGE_B(0, 1, 0); STAGE_B(0, 2, 0); STAGE_B(0, 3, 0);
    STAGE_A(0, 0, 0); STAGE_A(0, 2, 0); STAGE_A(0, 1, 0); STAGE_A(0, 3, 0);
    asm volatile("s_waitcnt vmcnt(2)" ::: "memory");
    BAR();

    for (int t = 0; t < NT; ++t) {
        const int  cur  = t & 1, nxt = cur ^ 1;
        const int  kt1  = (t + 1) * 64;
        const bool more = (t + 1 < NT);
        bf16x8 af[4][2], bn[4][2];

        // ---- phase 1: A rows m0-3 + B cols n0-1; stage next B0,B1 ----
#pragma unroll
        for (int m = 0; m < 4; ++m) { af[m][0] = LDA(m, 0); af[m][1] = LDA(m, 1); }
#pragma unroll
        for (int n = 0; n < 2; ++n) { bn[n][0] = LDB(n, 0); bn[n][1] = LDB(n, 1); }
        if (more) { STAGE_B(nxt, 0, kt1); STAGE_B(nxt, 1, kt1); }
        BAR();
        __builtin_amdgcn_s_setprio(1);
#pragma unroll
        for (int m = 0; m < 4; ++m)
#pragma unroll
            for (int n = 0; n < 2; ++n) {
                acc[m][n] = MFMA(af[m][0], bn[n][0], acc[m][n]);
                acc[m][n] = MFMA(af[m][1], bn[n][1], acc[m][n]);
            }
        __builtin_amdgcn_s_setprio(0);
        BAR();

        // ---- phase 2: B cols n2-3; stage next B2,B3; counted wait ----
#pragma unroll
        for (int n = 0; n < 2; ++n) { bn[n + 2][0] = LDB(n + 2, 0); bn[n + 2][1] = LDB(n + 2, 1); }
        if (more) { STAGE_B(nxt, 2, kt1); STAGE_B(nxt, 3, kt1); }
        if (t == NT - 1) { asm volatile("s_waitcnt vmcnt(0)" ::: "memory"); }
        else             { asm volatile("s_waitcnt vmcnt(4)" ::: "memory"); }  // retire this tile's A1,A3 (read in ph3)
        BAR();
        __builtin_amdgcn_s_setprio(1);
#pragma unroll
        for (int m = 0; m < 4; ++m)
#pragma unroll
            for (int n = 0; n < 2; ++n) {
                acc[m][n + 2] = MFMA(af[m][0], bn[n + 2][0], acc[m][n + 2]);
                acc[m][n + 2] = MFMA(af[m][1], bn[n + 2][1], acc[m][n + 2]);
            }
        __builtin_amdgcn_s_setprio(0);
        BAR();

        // ---- phase 3: A rows m4-7; stage next A0,A2 ----
#pragma unroll
        for (int m = 0; m < 4; ++m) { af[m][0] = LDA(m + 4, 0); af[m][1] = LDA(m + 4, 1); }
        if (more) { STAGE_A(nxt, 0, kt1); STAGE_A(nxt, 2, kt1); }
        BAR();
        __builtin_amdgcn_s_setprio(1);
#pragma unroll
        for (int m = 0; m < 4; ++m)
#pragma unroll
            for (int n = 0; n < 2; ++n) {
                acc[m + 4][n] = MFMA(af[m][0], bn[n][0], acc[m + 4][n]);
                acc[m + 4][n] = MFMA(af[m][1], bn[n][1], acc[m + 4][n]);
            }
        __builtin_amdgcn_s_setprio(0);
        BAR();

        // ---- phase 4: no reads; stage next A1,A3; counted wait for next ph1 ----
        if (more) {
            STAGE_A(nxt, 1, kt1); STAGE_A(nxt, 3, kt1);
            asm volatile("s_waitcnt vmcnt(2)" ::: "memory");  // next tile's B0-3,A0,A2 landed; A1,A3 stay in flight
        }
        BAR();
        __builtin_amdgcn_s_setprio(1);
#pragma unroll
        for (int m = 0; m < 4; ++m)
#pragma unroll
            for (int n = 0; n < 2; ++n) {
                acc[m + 4][n + 2] = MFMA(af[m][0], bn[n + 2][0], acc[m + 4][n + 2]);
                acc[m + 4][n + 2] = MFMA(af[m][1], bn[n + 2][1], acc[m + 4][n + 2]);
            }
        __builtin_amdgcn_s_setprio(0);
        BAR();
    }

    // ---- fused epilogue: dist = sqrt(max(s1 + s2 - 2*dot, EPS)); masked max/min ----
    int   tcol[4];
    float s2c[4];
#pragma unroll
    for (int n = 0; n < 4; ++n) {
        int col = bcol + wc * 64 + n * 16 + l15;
        tcol[n] = tgt[col];
        s2c[n]  = sq2[col];
    }
    const float INF = __uint_as_float(0x7f800000u);
#pragma unroll
    for (int m = 0; m < 8; ++m) {
#pragma unroll
        for (int reg = 0; reg < 4; ++reg) {
            // C/D layout (m89-verified): col = lane&15, row = (lane>>4)*4 + reg
            int   row  = brow + wr * 128 + m * 16 + lhi * 4 + reg;
            int   trow = tgt[row];
            float s1   = sq1[row];
            float pmax = 0.0f;
            float nmin = INF;
#pragma unroll
            for (int n = 0; n < 4; ++n) {
                float d2 = s1 + s2c[n] - 2.0f * acc[m][n][reg];
                float dd = sqrtf(fmaxf(d2, EPSF));
                if (trow == tcol[n]) pmax = fmaxf(pmax, dd);
                else                 nmin = fminf(nmin, dd);
            }
#pragma unroll
            for (int s = 1; s < 16; s <<= 1) {
                pmax = fmaxf(pmax, __shfl_xor(pmax, s));
                nmin = fminf(nmin, __shfl_xor(nmin, s));
            }
            if (l15 == 0) {
                atomicMax(&ap_bits[row], __float_as_uint(pmax));
                atomicMin(&an_bits[row], __float_as_uint(nmin));
            }
        }
    }
#undef STAGE_A
#undef STAGE_B
#undef LDA
#undef LDB
#undef BAR
#undef MFMA
}

// ---------------------------------------------------------------------------
// Kernel 3: loss = mean(relu(ap - an + margin)); prec = mean(an > ap)
// ---------------------------------------------------------------------------
__global__ __launch_bounds__(256) void finalize_kernel(
    const unsigned* __restrict__ ap_bits, const unsigned* __restrict__ an_bits,
    const float* __restrict__ marginp, float* __restrict__ out) {
    const int tid = threadIdx.x;
    const float margin = marginp[0];
    float ls = 0.f, ps = 0.f;
    for (int i = tid; i < N_ROWS; i += 256) {
        float a = __uint_as_float(ap_bits[i]);
        float b = __uint_as_float(an_bits[i]);
        ls += fmaxf(a - b + margin, 0.0f);
        ps += (b > a) ? 1.0f : 0.0f;
    }
    for (int s = 32; s > 0; s >>= 1) {
        ls += __shfl_down(ls, s);
        ps += __shfl_down(ps, s);
    }
    __shared__ float sl[4], sp[4];
    if ((tid & 63) == 0) { sl[tid >> 6] = ls; sp[tid >> 6] = ps; }
    __syncthreads();
    if (tid == 0) {
        ls = sl[0] + sl[1] + sl[2] + sl[3];
        ps = sp[0] + sp[1] + sp[2] + sp[3];
        out[0] = ls / (float)N_ROWS;
        out[1] = ps / (float)N_ROWS;
    }
}

// ---------------------------------------------------------------------------
extern "C" void kernel_launch(void* const* d_in, const int* in_sizes, int n_in,
                              void* d_out, int out_size, void* d_ws, size_t ws_size,
                              hipStream_t stream) {
    const float* m1  = (const float*)d_in[0];
    const float* m2  = (const float*)d_in[1];
    const int*   tgt = (const int*)d_in[2];
    const float* mrg = (const float*)d_in[3];

    char* ws = (char*)d_ws;
    unsigned short* abf = (unsigned short*)ws;                         // 16 MB bf16 modal1
    unsigned short* bbf = (unsigned short*)(ws + 16777216);            // 16 MB bf16 modal2
    float*    sq1 = (float*)(ws + 33554432);
    float*    sq2 = (float*)(ws + 33554432 + 16384);
    unsigned* ap  = (unsigned*)(ws + 33554432 + 32768);
    unsigned* an  = (unsigned*)(ws + 33554432 + 49152);

    float* outp = (float*)d_out;

    prep_kernel<<<2 * N_ROWS, 256, 0, stream>>>(m1, m2, abf, bbf, sq1, sq2, ap, an);
    dim3 grid(N_ROWS / 256, N_ROWS / 256);
    dist_gemm_kernel<<<grid, 512, 0, stream>>>(abf, bbf, sq1, sq2, tgt, ap, an);
    finalize_kernel<<<1, 256, 0, stream>>>(ap, an, mrg, outp);
}